// Round 1
// baseline (101.347 us; speedup 1.0000x reference)
//
#include <hip/hip_runtime.h>
#include <hip/hip_bf16.h>

#define DWT_LEN_C 84
#define TDIM 64
#define INNER 4096   // 64 * 8 * 8
#define KOUT 16

// db4 analysis filters
__device__ const float c_dec_lo[8] = {-0.010597401784997278f, 0.032883011666982945f, 0.030841381835986965f,
                                      -0.18703481171888114f, -0.02798376941698385f, 0.6308807679295904f,
                                      0.7148465705525415f, 0.23037781330885523f};
__device__ const float c_dec_hi[8] = {-0.23037781330885523f, 0.7148465705525415f, -0.6308807679295904f,
                                      -0.02798376941698385f, 0.18703481171888114f, 0.030841381835986965f,
                                      -0.032883011666982945f, -0.010597401784997278f};

// Single-level analysis filter bank (reflect pad, left pad always 6 for our sizes).
__device__ void afb1d_col(const float* v, int N, float* lo, float* hi, int M) {
    for (int i = 0; i < M; ++i) {
        float slo = 0.f, shi = 0.f;
        for (int j = 0; j < 8; ++j) {
            int idx = 2 * i + j - 6;
            if (idx < 0) idx = -idx;                  // reflect (exclude edge)
            if (idx >= N) idx = 2 * N - 2 - idx;
            float c = v[idx];
            slo = fmaf(c, c_dec_lo[7 - j], slo);      // conv = corr with reversed filter
            shi = fmaf(c, c_dec_hi[7 - j], shi);
        }
        lo[i] = slo; hi[i] = shi;
    }
}

// Build W_dwt[84][64]: column t = 3-level DWT applied to unit vector e_t.
// Row layout: [lo3 (14), hi1 (35), hi2 (21), hi3 (14)]
__global__ void build_wdwt(float* __restrict__ Wd) {
    int t = threadIdx.x;
    if (t >= TDIM) return;
    float v[64];
    for (int n = 0; n < 64; ++n) v[n] = (n == t) ? 1.f : 0.f;
    float lo1[35], hi1[35], lo2[21], hi2[21], lo3[14], hi3[14];
    afb1d_col(v, 64, lo1, hi1, 35);
    afb1d_col(lo1, 35, lo2, hi2, 21);
    afb1d_col(lo2, 21, lo3, hi3, 14);
    for (int i = 0; i < 14; ++i) Wd[(i) * TDIM + t] = lo3[i];
    for (int i = 0; i < 35; ++i) Wd[(14 + i) * TDIM + t] = hi1[i];
    for (int i = 0; i < 21; ++i) Wd[(49 + i) * TDIM + t] = hi2[i];
    for (int i = 0; i < 14; ++i) Wd[(70 + i) * TDIM + t] = hi3[i];
}

// W_eff[k][t*64+hw] = sum_dd conv_w[k][dd][hw] * W_dwt[dd][t]
__global__ void build_weff(const float* __restrict__ conv_w, const float* __restrict__ Wd,
                           float* __restrict__ Weff) {
    int idx = blockIdx.x * blockDim.x + threadIdx.x;   // k*4096 + t*64 + hw
    if (idx >= KOUT * INNER) return;
    int k = idx >> 12;
    int rem = idx & 4095;
    int t = rem >> 6;
    int hw = rem & 63;
    float s = 0.f;
    const float* cw = conv_w + (size_t)k * DWT_LEN_C * 64 + hw;
    for (int dd = 0; dd < DWT_LEN_C; ++dd)
        s = fmaf(cw[dd * 64], Wd[dd * TDIM + t], s);
    Weff[idx] = s;
}

// Main GEMV: out[b,k] = leakyrelu( dot(x[b,:4096], Weff[k,:4096]) + bias[k] )
// One wave handles 4 rows; lane l covers positions l*4 + 256*j (float4), j=0..15.
__global__ __launch_bounds__(256) void dwt_gemv(const float* __restrict__ x,
                                                const float* __restrict__ W,
                                                const float* __restrict__ bias,
                                                float* __restrict__ out, int B) {
    const int lane = threadIdx.x & 63;
    const int wid = threadIdx.x >> 6;
    const int group = blockIdx.x * 4 + wid;
    const long rowbase = (long)group * 4;

    const float* xp[4];
#pragma unroll
    for (int r = 0; r < 4; ++r) {
        long row = rowbase + r;
        if (row > B - 1) row = B - 1;   // clamped rows never stored
        xp[r] = x + row * (long)INNER;
    }

    float a[64];
#pragma unroll
    for (int i = 0; i < 64; ++i) a[i] = 0.f;

    const int lane4 = lane * 4;
#pragma unroll
    for (int j = 0; j < 16; ++j) {
        const int off = j * 256 + lane4;
        float4 xv[4];
#pragma unroll
        for (int r = 0; r < 4; ++r)
            xv[r] = *(const float4*)(xp[r] + off);
#pragma unroll
        for (int k = 0; k < 16; ++k) {
            float4 wv = *(const float4*)(W + k * INNER + off);
#pragma unroll
            for (int r = 0; r < 4; ++r) {
                float s = a[r * 16 + k];
                s = fmaf(xv[r].x, wv.x, s);
                s = fmaf(xv[r].y, wv.y, s);
                s = fmaf(xv[r].z, wv.z, s);
                s = fmaf(xv[r].w, wv.w, s);
                a[r * 16 + k] = s;
            }
        }
    }

    // Butterfly transpose-reduce: 64 partial values/lane -> lane l holds full sum
    // of value index bitrev6(l). 63 shfl+add total.
#pragma unroll
    for (int s = 0; s < 6; ++s) {
        const int m = 1 << s;
        const int h = 32 >> s;
#pragma unroll
        for (int v = 0; v < h; ++v) {
            float send = (lane & m) ? a[v] : a[v + h];
            float recv = __shfl_xor(send, m, 64);
            a[v] = ((lane & m) ? a[v + h] : a[v]) + recv;
        }
    }

    const unsigned vidx = __brev((unsigned)lane) >> 26;  // bitrev6
    const int k = vidx & 15;
    const int r = vidx >> 4;
    const long row = rowbase + r;
    if (row < B) {
        float val = a[0] + bias[k];
        val = (val >= 0.f) ? val : 1e-3f * val;
        out[row * KOUT + k] = val;
    }
}

extern "C" void kernel_launch(void* const* d_in, const int* in_sizes, int n_in,
                              void* d_out, int out_size, void* d_ws, size_t ws_size,
                              hipStream_t stream) {
    const float* x      = (const float*)d_in[0];
    const float* conv_w = (const float*)d_in[1];
    const float* conv_b = (const float*)d_in[2];
    float* out = (float*)d_out;
    const int B = in_sizes[0] / INNER;

    float* Wd   = (float*)d_ws;                         // 84*64 floats = 21.5 KB
    float* Weff = (float*)((char*)d_ws + 32768);        // 16*4096 floats = 256 KB

    build_wdwt<<<1, 64, 0, stream>>>(Wd);
    build_weff<<<(KOUT * INNER) / 256, 256, 0, stream>>>(conv_w, Wd, Weff);

    const int groups = (B + 3) / 4;        // 4 rows per wave
    const int blocks = (groups + 3) / 4;   // 4 waves per block
    dwt_gemv<<<blocks, 256, 0, stream>>>(x, Weff, conv_b, out, B);
}

// Round 2
// 87.270 us; speedup vs baseline: 1.1613x; 1.1613x over previous
//
#include <hip/hip_runtime.h>
#include <hip/hip_bf16.h>

#define DWT_LEN_C 84
#define TDIM 64
#define INNER 4096   // 64 * 8 * 8
#define KOUT 16

// db4 analysis filters
__device__ const float c_dec_lo[8] = {-0.010597401784997278f, 0.032883011666982945f, 0.030841381835986965f,
                                      -0.18703481171888114f, -0.02798376941698385f, 0.6308807679295904f,
                                      0.7148465705525415f, 0.23037781330885523f};
__device__ const float c_dec_hi[8] = {-0.23037781330885523f, 0.7148465705525415f, -0.6308807679295904f,
                                      -0.02798376941698385f, 0.18703481171888114f, 0.030841381835986965f,
                                      -0.032883011666982945f, -0.010597401784997278f};

// Single-level analysis filter bank (reflect pad; left pad 6 for our sizes).
__device__ void afb1d_col(const float* v, int N, float* lo, float* hi, int M) {
    for (int i = 0; i < M; ++i) {
        float slo = 0.f, shi = 0.f;
        for (int j = 0; j < 8; ++j) {
            int idx = 2 * i + j - 6;
            if (idx < 0) idx = -idx;                  // reflect (exclude edge)
            if (idx >= N) idx = 2 * N - 2 - idx;
            float c = v[idx];
            slo = fmaf(c, c_dec_lo[7 - j], slo);      // conv = corr with reversed filter
            shi = fmaf(c, c_dec_hi[7 - j], shi);
        }
        lo[i] = slo; hi[i] = shi;
    }
}

// Fused: each block rebuilds W_dwt[84][64] in LDS (cheap, ~1 us), then computes
// its 256 elements of W_eff[k][t*64+hw] = sum_dd conv_w[k][dd][hw] * W_dwt[dd][t]
__global__ __launch_bounds__(256) void build_weff_fused(const float* __restrict__ conv_w,
                                                        float* __restrict__ Weff) {
    __shared__ float Wd[DWT_LEN_C][TDIM];
    const int t0 = threadIdx.x;
    if (t0 < TDIM) {
        float v[64];
        for (int n = 0; n < 64; ++n) v[n] = (n == t0) ? 1.f : 0.f;
        float lo1[35], hi1[35], lo2[21], hi2[21], lo3[14], hi3[14];
        afb1d_col(v, 64, lo1, hi1, 35);
        afb1d_col(lo1, 35, lo2, hi2, 21);
        afb1d_col(lo2, 21, lo3, hi3, 14);
        for (int i = 0; i < 14; ++i) Wd[i][t0] = lo3[i];
        for (int i = 0; i < 35; ++i) Wd[14 + i][t0] = hi1[i];
        for (int i = 0; i < 21; ++i) Wd[49 + i][t0] = hi2[i];
        for (int i = 0; i < 14; ++i) Wd[70 + i][t0] = hi3[i];
    }
    __syncthreads();

    const int idx = blockIdx.x * 256 + threadIdx.x;    // k*4096 + t*64 + hw
    const int k = idx >> 12;
    const int rem = idx & 4095;
    const int t = rem >> 6;
    const int hw = rem & 63;
    float s = 0.f;
    const float* cw = conv_w + (size_t)k * DWT_LEN_C * 64 + hw;
#pragma unroll 4
    for (int dd = 0; dd < DWT_LEN_C; ++dd)
        s = fmaf(cw[dd * 64], Wd[dd][t], s);
    Weff[idx] = s;
}

// Main GEMV: out[b,k] = leakyrelu( dot(x[b,:4096], Weff[k,:4096]) + bias[k] )
// One wave handles 4 rows; lane l covers positions l*4 + 256*j (float4), j=0..15.
// launch_bounds(256,4): cap VGPRs at 128 so all 4 waves/SIMD are resident.
__global__ __launch_bounds__(256, 4) void dwt_gemv(const float* __restrict__ x,
                                                   const float* __restrict__ W,
                                                   const float* __restrict__ bias,
                                                   float* __restrict__ out, int B) {
    const int lane = threadIdx.x & 63;
    const int wid = threadIdx.x >> 6;
    const int group = blockIdx.x * 4 + wid;
    const long rowbase = (long)group * 4;

    const float* xp[4];
#pragma unroll
    for (int r = 0; r < 4; ++r) {
        long row = rowbase + r;
        if (row > B - 1) row = B - 1;   // clamped rows never stored
        xp[r] = x + row * (long)INNER;
    }

    float a[64];
#pragma unroll
    for (int i = 0; i < 64; ++i) a[i] = 0.f;

    const int lane4 = lane * 4;

    // prologue: load j=0
    float4 xv[4];
#pragma unroll
    for (int r = 0; r < 4; ++r) xv[r] = *(const float4*)(xp[r] + lane4);

#pragma unroll 1
    for (int j = 0; j < 15; ++j) {
        const int off = j * 256 + lane4;
        // prefetch next j's x (HBM) while computing current
        float4 xn[4];
#pragma unroll
        for (int r = 0; r < 4; ++r)
            xn[r] = *(const float4*)(xp[r] + off + 256);
#pragma unroll
        for (int k = 0; k < 16; ++k) {
            float4 wv = *(const float4*)(W + k * INNER + off);
#pragma unroll
            for (int r = 0; r < 4; ++r) {
                float s = a[r * 16 + k];
                s = fmaf(xv[r].x, wv.x, s);
                s = fmaf(xv[r].y, wv.y, s);
                s = fmaf(xv[r].z, wv.z, s);
                s = fmaf(xv[r].w, wv.w, s);
                a[r * 16 + k] = s;
            }
        }
#pragma unroll
        for (int r = 0; r < 4; ++r) xv[r] = xn[r];
    }
    // epilogue: j = 15
    {
        const int off = 15 * 256 + lane4;
#pragma unroll
        for (int k = 0; k < 16; ++k) {
            float4 wv = *(const float4*)(W + k * INNER + off);
#pragma unroll
            for (int r = 0; r < 4; ++r) {
                float s = a[r * 16 + k];
                s = fmaf(xv[r].x, wv.x, s);
                s = fmaf(xv[r].y, wv.y, s);
                s = fmaf(xv[r].z, wv.z, s);
                s = fmaf(xv[r].w, wv.w, s);
                a[r * 16 + k] = s;
            }
        }
    }

    // Butterfly transpose-reduce: lane l ends with full sum of value bitrev6(l).
#pragma unroll
    for (int s = 0; s < 6; ++s) {
        const int m = 1 << s;
        const int h = 32 >> s;
#pragma unroll
        for (int v = 0; v < h; ++v) {
            float send = (lane & m) ? a[v] : a[v + h];
            float recv = __shfl_xor(send, m, 64);
            a[v] = ((lane & m) ? a[v + h] : a[v]) + recv;
        }
    }

    const unsigned vidx = __brev((unsigned)lane) >> 26;  // bitrev6
    const int k = vidx & 15;
    const int r = vidx >> 4;
    const long row = rowbase + r;
    if (row < B) {
        float val = a[0] + bias[k];
        val = (val >= 0.f) ? val : 1e-3f * val;
        out[row * KOUT + k] = val;
    }
}

extern "C" void kernel_launch(void* const* d_in, const int* in_sizes, int n_in,
                              void* d_out, int out_size, void* d_ws, size_t ws_size,
                              hipStream_t stream) {
    const float* x      = (const float*)d_in[0];
    const float* conv_w = (const float*)d_in[1];
    const float* conv_b = (const float*)d_in[2];
    float* out = (float*)d_out;
    const int B = in_sizes[0] / INNER;

    float* Weff = (float*)d_ws;                         // 16*4096 floats = 256 KB

    build_weff_fused<<<(KOUT * INNER) / 256, 256, 0, stream>>>(conv_w, Weff);

    const int groups = (B + 3) / 4;        // 4 rows per wave
    const int blocks = (groups + 3) / 4;   // 4 waves per block
    dwt_gemv<<<blocks, 256, 0, stream>>>(x, Weff, conv_b, out, B);
}